// Round 2
// baseline (564.345 us; speedup 1.0000x reference)
//
#include <hip/hip_runtime.h>
#include <hip/hip_bf16.h>

// QuantizedSimpleSSM — round 2: fp32 sequential-FMA accumulation to bitwise-match
// the numpy (OpenBLAS) reference's per-element accumulation chains.
//
// Pipeline:
//  1) quantk: A,B,C,D -> q8 (bitwise replica of reference to_float8)
//  2) gemm_R: R[b][t][n] = sum_d u[b][d][t] * Bq[n][d]   (fp32 fma chain, k ascending)
//  3) recur : per-b elementwise recurrence (mul-then-add, no FMA), S[b][n][t]
//  4) gemm_Y: Y[b][o][t] = q8( (sum_n S*Cq) + (sum_d u*Dq) )  (two fp32 fma chains)

#define DINX 512
#define LSEQ 512
#define NDIM 512

__device__ __forceinline__ float q8(float x) {
    float xa = fabsf(x);
    float w  = __fadd_rn(xa, 1e-8f);
    int e = (int)((__float_as_uint(w) >> 23) & 0xFFu) - 127;   // floor(log2(w)), w>0 normal
    e = e < -7 ? -7 : (e > 7 ? 7 : e);
    float p  = __int_as_float((unsigned)((e + 127) << 23));     // exact 2^e
    float t  = __fmul_rn(__fsub_rn(__fdiv_rn(xa, p), 1.0f), 8.0f);
    float m  = __fmul_rn(rintf(t), 0.125f);                     // half-to-even like np.round
    float r  = __fmul_rn(__fadd_rn(1.0f, m), p);
    return copysignf(r, x);                                     // x==0 -> r==0
}

__global__ void quantk(const float* __restrict__ in, float* __restrict__ out, int n) {
    int i = blockIdx.x * blockDim.x + threadIdx.x;
    if (i < n) out[i] = q8(in[i]);
}

// R[b][t][n] = sum_d u[b][d][t] * Bq[n][d]; fp32 fma chain, d ascending.
// grid (t_tiles=8, n_tiles=8, b=32), block 256, tile 64x64, K-step 16, 4x4/thread.
__global__ __launch_bounds__(256) void gemm_R(const float* __restrict__ u,
                                              const float* __restrict__ Bq,
                                              float* __restrict__ R) {
    __shared__ float As[16][66];   // [k][t]
    __shared__ float Bs[16][66];   // [k][n]
    const int b  = blockIdx.z;
    const int t0 = blockIdx.x * 64, n0 = blockIdx.y * 64;
    const int tid = threadIdx.x;
    const int tx = tid & 15, ty = tid >> 4;
    const int lk = tid >> 4, ltc = (tid & 15) * 4;   // As stage: k row, 4 t's
    const int lnn = tid >> 2, lkk = (tid & 3) * 4;   // Bs stage: n row, 4 k's
    const float* ub = u + (size_t)b * (DINX * LSEQ);
    float acc[4][4] = {};
    for (int k0 = 0; k0 < DINX; k0 += 16) {
        float4 av = *(const float4*)(ub + (k0 + lk) * LSEQ + t0 + ltc);
        float4 bv = *(const float4*)(Bq + (n0 + lnn) * DINX + k0 + lkk);
        As[lk][ltc + 0] = av.x; As[lk][ltc + 1] = av.y;
        As[lk][ltc + 2] = av.z; As[lk][ltc + 3] = av.w;
        Bs[lkk + 0][lnn] = bv.x; Bs[lkk + 1][lnn] = bv.y;
        Bs[lkk + 2][lnn] = bv.z; Bs[lkk + 3][lnn] = bv.w;
        __syncthreads();
#pragma unroll
        for (int k = 0; k < 16; ++k) {
            float a[4], bb[4];
#pragma unroll
            for (int i = 0; i < 4; ++i) a[i]  = As[k][tx * 4 + i];
#pragma unroll
            for (int j = 0; j < 4; ++j) bb[j] = Bs[k][ty * 4 + j];
#pragma unroll
            for (int i = 0; i < 4; ++i)
#pragma unroll
                for (int j = 0; j < 4; ++j) acc[i][j] = fmaf(a[i], bb[j], acc[i][j]);
        }
        __syncthreads();
    }
    float* Rb = R + (size_t)b * (LSEQ * NDIM);
#pragma unroll
    for (int i = 0; i < 4; ++i) {
        float4 st = make_float4(acc[i][0], acc[i][1], acc[i][2], acc[i][3]);
        *(float4*)(Rb + (t0 + tx * 4 + i) * NDIM + n0 + ty * 4) = st;
    }
}

// Per-batch recurrence. grid 32, block 512 (thread = n). Writes S[b][n][t] (fp32)
// via an LDS transpose every 16 steps so gemm_Y can read coalesced along t.
__global__ __launch_bounds__(512) void recur(const float* __restrict__ R,
                                             const float* __restrict__ Aq,
                                             float* __restrict__ S) {
    __shared__ float tile[16][516];
    const int b = blockIdx.x;
    const int n = threadIdx.x;
    const float a = Aq[n];
    const float* Rb = R + (size_t)b * (LSEQ * NDIM);
    float* Sb = S + (size_t)b * (NDIM * LSEQ);
    float s = 0.0f;
    const int c = (n & 3) * 4;
    const int rbase = n >> 2;                 // 0..127
    for (int t0 = 0; t0 < LSEQ; t0 += 16) {
#pragma unroll
        for (int tt = 0; tt < 16; ++tt) {
            float r = Rb[(t0 + tt) * NDIM + n];
            s = q8(__fadd_rn(__fmul_rn(s, a), r));   // mul-then-add like numpy, no FMA
            tile[tt][n] = s;
        }
        __syncthreads();
#pragma unroll
        for (int p = 0; p < 4; ++p) {
            int row = p * 128 + rbase;
            float4 v = make_float4(tile[c + 0][row], tile[c + 1][row],
                                   tile[c + 2][row], tile[c + 3][row]);
            *(float4*)(Sb + row * LSEQ + t0 + c) = v;
        }
        __syncthreads();
    }
}

// Y[b][o][t] = q8( (sum_n S[b][n][t]*Cq[o][n]) + (sum_d u[b][d][t]*Dq[o][d]) )
// Two fp32 fma chains (k ascending), added in fp32, then q8 — matching numpy's
// "matmul + matmul, add, quantize" exactly.
__global__ __launch_bounds__(256) void gemm_Y(const float* __restrict__ u,
                                              const float* __restrict__ S,
                                              const float* __restrict__ Cq,
                                              const float* __restrict__ Dq,
                                              float* __restrict__ Y) {
    __shared__ float Xs[16][66];   // [k][t]
    __shared__ float Ws[16][66];   // [k][o]
    const int b  = blockIdx.z;
    const int t0 = blockIdx.x * 64, o0 = blockIdx.y * 64;
    const int tid = threadIdx.x;
    const int tx = tid & 15, ty = tid >> 4;
    const int lk = tid >> 4, ltc = (tid & 15) * 4;
    const int loo = tid >> 2, lkk = (tid & 3) * 4;
    const float* Sb = S + (size_t)b * (NDIM * LSEQ);
    const float* ub = u + (size_t)b * (DINX * LSEQ);
    float acc[4][4] = {};
    float c1[4][4];

    // pass 1: K over n, X = S[b] ([n][t]), W = Cq ([o][n])
    for (int k0 = 0; k0 < NDIM; k0 += 16) {
        float4 xv = *(const float4*)(Sb + (k0 + lk) * LSEQ + t0 + ltc);
        float4 wv = *(const float4*)(Cq + (o0 + loo) * NDIM + k0 + lkk);
        Xs[lk][ltc + 0] = xv.x; Xs[lk][ltc + 1] = xv.y;
        Xs[lk][ltc + 2] = xv.z; Xs[lk][ltc + 3] = xv.w;
        Ws[lkk + 0][loo] = wv.x; Ws[lkk + 1][loo] = wv.y;
        Ws[lkk + 2][loo] = wv.z; Ws[lkk + 3][loo] = wv.w;
        __syncthreads();
#pragma unroll
        for (int k = 0; k < 16; ++k) {
            float a[4], bb[4];
#pragma unroll
            for (int i = 0; i < 4; ++i) a[i]  = Xs[k][tx * 4 + i];
#pragma unroll
            for (int j = 0; j < 4; ++j) bb[j] = Ws[k][ty * 4 + j];
#pragma unroll
            for (int i = 0; i < 4; ++i)
#pragma unroll
                for (int j = 0; j < 4; ++j) acc[i][j] = fmaf(a[i], bb[j], acc[i][j]);
        }
        __syncthreads();
    }
#pragma unroll
    for (int i = 0; i < 4; ++i)
#pragma unroll
        for (int j = 0; j < 4; ++j) { c1[i][j] = acc[i][j]; acc[i][j] = 0.0f; }

    // pass 2: K over d, X = u[b] ([d][t]), W = Dq ([o][d])
    for (int k0 = 0; k0 < DINX; k0 += 16) {
        float4 xv = *(const float4*)(ub + (k0 + lk) * LSEQ + t0 + ltc);
        float4 wv = *(const float4*)(Dq + (o0 + loo) * DINX + k0 + lkk);
        Xs[lk][ltc + 0] = xv.x; Xs[lk][ltc + 1] = xv.y;
        Xs[lk][ltc + 2] = xv.z; Xs[lk][ltc + 3] = xv.w;
        Ws[lkk + 0][loo] = wv.x; Ws[lkk + 1][loo] = wv.y;
        Ws[lkk + 2][loo] = wv.z; Ws[lkk + 3][loo] = wv.w;
        __syncthreads();
#pragma unroll
        for (int k = 0; k < 16; ++k) {
            float a[4], bb[4];
#pragma unroll
            for (int i = 0; i < 4; ++i) a[i]  = Xs[k][tx * 4 + i];
#pragma unroll
            for (int j = 0; j < 4; ++j) bb[j] = Ws[k][ty * 4 + j];
#pragma unroll
            for (int i = 0; i < 4; ++i)
#pragma unroll
                for (int j = 0; j < 4; ++j) acc[i][j] = fmaf(a[i], bb[j], acc[i][j]);
        }
        __syncthreads();
    }

    float* Yb = Y + (size_t)b * (NDIM * LSEQ);
    float yv[4][4];
#pragma unroll
    for (int i = 0; i < 4; ++i)
#pragma unroll
        for (int j = 0; j < 4; ++j)
            yv[i][j] = q8(__fadd_rn(c1[i][j], acc[i][j]));
#pragma unroll
    for (int j = 0; j < 4; ++j) {
        float4 st = make_float4(yv[0][j], yv[1][j], yv[2][j], yv[3][j]);
        *(float4*)(Yb + (o0 + ty * 4 + j) * LSEQ + t0 + tx * 4) = st;
    }
}

extern "C" void kernel_launch(void* const* d_in, const int* in_sizes, int n_in,
                              void* d_out, int out_size, void* d_ws, size_t ws_size,
                              hipStream_t stream) {
    const float* u = (const float*)d_in[0];   // (32, 512, 512)
    const float* A = (const float*)d_in[1];   // (512,)
    const float* B = (const float*)d_in[2];   // (512, 512)
    const float* C = (const float*)d_in[3];   // (512, 512)
    const float* D = (const float*)d_in[4];   // (512, 512)

    float* ws = (float*)d_ws;
    float* Aq = ws;                     // 512
    float* Bq = Aq + 512;               // 262144
    float* Cq = Bq + 262144;            // 262144
    float* Dq = Cq + 262144;            // 262144
    float* R  = Dq + 262144;            // 8388608  [b][t][n]
    float* S  = R  + 8388608;           // 8388608  [b][n][t]
    float* Y  = (float*)d_out;          // 8388608  [b][o][t]

    quantk<<<2, 256, 0, stream>>>(A, Aq, 512);
    quantk<<<1024, 256, 0, stream>>>(B, Bq, 262144);
    quantk<<<1024, 256, 0, stream>>>(C, Cq, 262144);
    quantk<<<1024, 256, 0, stream>>>(D, Dq, 262144);

    gemm_R<<<dim3(8, 8, 32), 256, 0, stream>>>(u, Bq, R);
    recur<<<32, 512, 0, stream>>>(R, Aq, S);
    gemm_Y<<<dim3(8, 8, 32), 256, 0, stream>>>(u, S, Cq, Dq, Y);
}

// Round 3
// 450.118 us; speedup vs baseline: 1.2538x; 1.2538x over previous
//
#include <hip/hip_runtime.h>
#include <hip/hip_bf16.h>

// QuantizedSimpleSSM — round 3: 128x128 tiles, 8x8 register blocking,
// quant+transpose fused so all gemm staging reads are row-contiguous.
// Numerics contract (absmax 0.0 in R2): every output element is a single fp32
// FMA chain in strictly ascending k — preserved exactly here.

#define DINX 512
#define LSEQ 512
#define NDIM 512

__device__ __forceinline__ float q8(float x) {
    float xa = fabsf(x);
    float w  = __fadd_rn(xa, 1e-8f);
    int e = (int)((__float_as_uint(w) >> 23) & 0xFFu) - 127;   // floor(log2(w)), w>0 normal
    e = e < -7 ? -7 : (e > 7 ? 7 : e);
    float p  = __int_as_float((unsigned)((e + 127) << 23));     // exact 2^e
    float t  = __fmul_rn(__fsub_rn(__fdiv_rn(xa, p), 1.0f), 8.0f);
    float m  = __fmul_rn(rintf(t), 0.125f);                     // half-to-even like np.round
    float r  = __fmul_rn(__fadd_rn(1.0f, m), p);
    return copysignf(r, x);
}

__global__ void quantk(const float* __restrict__ in, float* __restrict__ out, int n) {
    int i = blockIdx.x * blockDim.x + threadIdx.x;
    if (i < n) out[i] = q8(in[i]);
}

// out[c][r] = q8(in[r][c]) for 512x512. grid (16,16), block 256.
__global__ __launch_bounds__(256) void quantT(const float* __restrict__ in,
                                              float* __restrict__ out) {
    __shared__ float tl[32][33];
    const int r0 = blockIdx.y * 32, c0 = blockIdx.x * 32;
    const int x = threadIdx.x & 31, y = threadIdx.x >> 5;   // 32 x 8
#pragma unroll
    for (int i = 0; i < 32; i += 8)
        tl[y + i][x] = q8(in[(r0 + y + i) * 512 + c0 + x]);
    __syncthreads();
#pragma unroll
    for (int i = 0; i < 32; i += 8)
        out[(c0 + y + i) * 512 + r0 + x] = tl[x][y + i];
}

// One K-pass: acc[i][j] += sum_k X[k][m0+tx*8+i] * W[k][n0+ty*8+j], k ascending.
// X, W are [KTOT][512] row-major. Xs/Ws are [16][128] LDS tiles.
__device__ __forceinline__ void gemm_pass(const float* __restrict__ X,
                                          const float* __restrict__ W,
                                          int m0, int n0, int KTOT,
                                          float (&acc)[8][8],
                                          float (*Xs)[128], float (*Ws)[128],
                                          int tid) {
    const int tx = tid & 15, ty = tid >> 4;
    const int srow = tid >> 4;          // 0..15: k row within tile
    const int sseg = tid & 15;          // 0..15: 8-float segment
    for (int k0 = 0; k0 < KTOT; k0 += 16) {
        const float* xp = X + (size_t)(k0 + srow) * 512 + m0 + sseg * 8;
        const float* wp = W + (size_t)(k0 + srow) * 512 + n0 + sseg * 8;
        float4 x0 = *(const float4*)xp;
        float4 x1 = *(const float4*)(xp + 4);
        float4 w0 = *(const float4*)wp;
        float4 w1 = *(const float4*)(wp + 4);
        __syncthreads();                 // prev-tile reads done before overwrite
        *(float4*)&Xs[srow][sseg * 8]     = x0;
        *(float4*)&Xs[srow][sseg * 8 + 4] = x1;
        *(float4*)&Ws[srow][sseg * 8]     = w0;
        *(float4*)&Ws[srow][sseg * 8 + 4] = w1;
        __syncthreads();
#pragma unroll
        for (int k = 0; k < 16; ++k) {
            float a[8], b[8];
            *(float4*)&a[0] = *(const float4*)&Xs[k][tx * 8];
            *(float4*)&a[4] = *(const float4*)&Xs[k][tx * 8 + 4];
            *(float4*)&b[0] = *(const float4*)&Ws[k][ty * 8];
            *(float4*)&b[4] = *(const float4*)&Ws[k][ty * 8 + 4];
#pragma unroll
            for (int i = 0; i < 8; ++i)
#pragma unroll
                for (int j = 0; j < 8; ++j)
                    acc[i][j] = fmaf(a[i], b[j], acc[i][j]);
        }
    }
}

// R[b][t][n] = sum_d u[b][d][t] * Bqt[d][n]. grid (4,4,32), block 256.
__global__ __launch_bounds__(256) void gemm_R(const float* __restrict__ u,
                                              const float* __restrict__ Bqt,
                                              float* __restrict__ R) {
    __shared__ float Xs[16][128];
    __shared__ float Ws[16][128];
    const int b  = blockIdx.z;
    const int t0 = blockIdx.x * 128, n0 = blockIdx.y * 128;
    const int tid = threadIdx.x;
    const int tx = tid & 15, ty = tid >> 4;
    const float* ub = u + (size_t)b * (DINX * LSEQ);
    float acc[8][8] = {};
    gemm_pass(ub, Bqt, t0, n0, DINX, acc, Xs, Ws, tid);
    float* Rb = R + (size_t)b * (LSEQ * NDIM);
#pragma unroll
    for (int i = 0; i < 8; ++i) {
        float* row = Rb + (size_t)(t0 + tx * 8 + i) * NDIM + n0 + ty * 8;
        *(float4*)row       = make_float4(acc[i][0], acc[i][1], acc[i][2], acc[i][3]);
        *(float4*)(row + 4) = make_float4(acc[i][4], acc[i][5], acc[i][6], acc[i][7]);
    }
}

// Per-batch recurrence (bitwise np: mul-then-add, q8). Writes S[b][n][t].
__global__ __launch_bounds__(512) void recur(const float* __restrict__ R,
                                             const float* __restrict__ Aq,
                                             float* __restrict__ S) {
    __shared__ float tile[16][516];
    const int b = blockIdx.x;
    const int n = threadIdx.x;
    const float a = Aq[n];
    const float* Rb = R + (size_t)b * (LSEQ * NDIM);
    float* Sb = S + (size_t)b * (NDIM * LSEQ);
    float s = 0.0f;
    const int c = (n & 3) * 4;
    const int rbase = n >> 2;
    for (int t0 = 0; t0 < LSEQ; t0 += 16) {
#pragma unroll
        for (int tt = 0; tt < 16; ++tt) {
            float r = Rb[(t0 + tt) * NDIM + n];
            s = q8(__fadd_rn(__fmul_rn(s, a), r));
            tile[tt][n] = s;
        }
        __syncthreads();
#pragma unroll
        for (int p = 0; p < 4; ++p) {
            int row = p * 128 + rbase;
            float4 v = make_float4(tile[c + 0][row], tile[c + 1][row],
                                   tile[c + 2][row], tile[c + 3][row]);
            *(float4*)(Sb + row * LSEQ + t0 + c) = v;
        }
        __syncthreads();
    }
}

// Y[b][o][t] = q8( (sum_n S[n][t]*Cqt[n][o]) + (sum_d u[d][t]*Dqt[d][o]) )
__global__ __launch_bounds__(256) void gemm_Y(const float* __restrict__ u,
                                              const float* __restrict__ S,
                                              const float* __restrict__ Cqt,
                                              const float* __restrict__ Dqt,
                                              float* __restrict__ Y) {
    __shared__ float Xs[16][128];
    __shared__ float Ws[16][128];
    const int b  = blockIdx.z;
    const int t0 = blockIdx.x * 128, o0 = blockIdx.y * 128;
    const int tid = threadIdx.x;
    const int tx = tid & 15, ty = tid >> 4;
    const float* Sb = S + (size_t)b * (NDIM * LSEQ);
    const float* ub = u + (size_t)b * (DINX * LSEQ);
    float acc[8][8] = {};
    float c1[8][8];
    gemm_pass(Sb, Cqt, t0, o0, NDIM, acc, Xs, Ws, tid);
#pragma unroll
    for (int i = 0; i < 8; ++i)
#pragma unroll
        for (int j = 0; j < 8; ++j) { c1[i][j] = acc[i][j]; acc[i][j] = 0.0f; }
    __syncthreads();
    gemm_pass(ub, Dqt, t0, o0, DINX, acc, Xs, Ws, tid);

    float* Yb = Y + (size_t)b * (NDIM * LSEQ);
#pragma unroll
    for (int j = 0; j < 8; ++j) {
        float y0[4], y1[4];
#pragma unroll
        for (int i = 0; i < 4; ++i) y0[i] = q8(__fadd_rn(c1[i][j], acc[i][j]));
#pragma unroll
        for (int i = 0; i < 4; ++i) y1[i] = q8(__fadd_rn(c1[4 + i][j], acc[4 + i][j]));
        float* row = Yb + (size_t)(o0 + ty * 8 + j) * LSEQ + t0 + tx * 8;
        *(float4*)row       = make_float4(y0[0], y0[1], y0[2], y0[3]);
        *(float4*)(row + 4) = make_float4(y1[0], y1[1], y1[2], y1[3]);
    }
}

extern "C" void kernel_launch(void* const* d_in, const int* in_sizes, int n_in,
                              void* d_out, int out_size, void* d_ws, size_t ws_size,
                              hipStream_t stream) {
    const float* u = (const float*)d_in[0];   // (32, 512, 512)
    const float* A = (const float*)d_in[1];   // (512,)
    const float* B = (const float*)d_in[2];   // (512, 512)
    const float* C = (const float*)d_in[3];   // (512, 512)
    const float* D = (const float*)d_in[4];   // (512, 512)

    float* ws  = (float*)d_ws;
    float* Aq  = ws;                    // 512
    float* Bqt = Aq + 512;              // 262144  [d][n]
    float* Cqt = Bqt + 262144;          // 262144  [n][o]
    float* Dqt = Cqt + 262144;          // 262144  [d][o]
    float* R   = Dqt + 262144;          // 8388608 [b][t][n]
    float* S   = R + 8388608;           // 8388608 [b][n][t]
    float* Y   = (float*)d_out;         // 8388608 [b][o][t]

    quantk<<<2, 256, 0, stream>>>(A, Aq, 512);
    quantT<<<dim3(16, 16), 256, 0, stream>>>(B, Bqt);   // Bqt[d][n] = q8(B[n][d])
    quantT<<<dim3(16, 16), 256, 0, stream>>>(C, Cqt);   // Cqt[n][o] = q8(C[o][n])
    quantT<<<dim3(16, 16), 256, 0, stream>>>(D, Dqt);   // Dqt[d][o] = q8(D[o][d])

    gemm_R<<<dim3(4, 4, 32), 256, 0, stream>>>(u, Bqt, R);
    recur<<<32, 512, 0, stream>>>(R, Aq, S);
    gemm_Y<<<dim3(4, 4, 32), 256, 0, stream>>>(u, S, Cqt, Dqt, Y);
}